// Round 2
// baseline (1096.685 us; speedup 1.0000x reference)
//
#include <hip/hip_runtime.h>

#define TC 32            // channels per block tile
#define NT 256           // threads per block
#define GPC (NT / TC)    // 8 line-groups per channel tile

// LDS: buf[line(90)][kd(3)][TC] of float2 (re,im) -> 90*3*32*8B = 69120 B
// index = ((line*3)+kd)*TC + cl
// All LDS accesses: lane cl reads address base + 8*cl -> 32 lanes span 256B,
// i.e. each bank hit by exactly 2 lanes of the wave64 -> conflict-free (2-way free).

__global__ __launch_bounds__(NT, 2)
void gf_kernel(const float* __restrict__ x, const float* __restrict__ cw,
               float* __restrict__ y, int nch)
{
    // twiddle tables: cos/sin(2*pi*m/N); folded to literals after full unroll
    static constexpr float C5[5]  = {1.f, 0.30901699437494745f, -0.8090169943749473f,
                                     -0.8090169943749473f, 0.30901699437494745f};
    static constexpr float S5[5]  = {0.f, 0.9510565162951535f, 0.5877852522924732f,
                                     -0.5877852522924732f, -0.9510565162951535f};
    static constexpr float C10[10] = {1.f, 0.8090169943749474f, 0.30901699437494745f,
                                      -0.30901699437494745f, -0.8090169943749474f, -1.f,
                                      -0.8090169943749474f, -0.30901699437494745f,
                                      0.30901699437494745f, 0.8090169943749474f};
    static constexpr float S10[10] = {0.f, 0.5877852522924731f, 0.9510565162951535f,
                                      0.9510565162951535f, 0.5877852522924731f, 0.f,
                                      -0.5877852522924731f, -0.9510565162951535f,
                                      -0.9510565162951535f, -0.5877852522924731f};
    static constexpr float C9[9] = {1.f, 0.766044443118978f, 0.17364817766693041f, -0.5f,
                                    -0.9396926207859084f, -0.9396926207859084f, -0.5f,
                                    0.17364817766693041f, 0.766044443118978f};
    static constexpr float S9[9] = {0.f, 0.6427876096865393f, 0.984807753012208f,
                                    0.8660254037844387f, 0.3420201433256689f,
                                    -0.3420201433256689f, -0.8660254037844387f,
                                    -0.984807753012208f, -0.6427876096865393f};

    __shared__ float2 buf[90 * 3 * TC];

    const int b  = blockIdx.x;
    const int c0 = blockIdx.y * TC;
    const int t  = threadIdx.x;
    const int cl = t & (TC - 1);
    const int g  = t >> 5;                 // 0..GPC-1
    const int c  = c0 + cl;
    const bool cv = (c < nch);

    const float* xb = x + (size_t)b * 450 * nch + c;
    float*       yb = y + (size_t)b * 450 * nch + c;
    const float* wb = cw + (size_t)c * 2;  // weight base for this channel

    // ---------------- S1: rfft along D (5 real -> 3 complex), global -> LDS
    for (int l = g; l < 90; l += GPC) {
        float v0 = 0.f, v1 = 0.f, v2 = 0.f, v3 = 0.f, v4 = 0.f;
        if (cv) {
            const float* p = xb + (size_t)l * 5 * nch;
            v0 = p[0];       v1 = p[nch];     v2 = p[2 * nch];
            v3 = p[3 * nch]; v4 = p[4 * nch];
        }
        float2* out = &buf[(l * 3) * TC + cl];
        out[0] = make_float2(v0 + v1 + v2 + v3 + v4, 0.f);
        // k=1: m = d%5
        float r1 = v0 + v1 * C5[1] + v2 * C5[2] + v3 * C5[3] + v4 * C5[4];
        float i1 = -(v1 * S5[1] + v2 * S5[2] + v3 * S5[3] + v4 * S5[4]);
        out[TC] = make_float2(r1, i1);
        // k=2: m = (2d)%5
        float r2 = v0 + v1 * C5[2] + v2 * C5[4] + v3 * C5[1] + v4 * C5[3];
        float i2 = -(v1 * S5[2] + v2 * S5[4] + v3 * S5[1] + v4 * S5[3]);
        out[2 * TC] = make_float2(r2, i2);
    }
    __syncthreads();

    // ---------------- S2: forward 10-pt DFT along W; 27 sets (h,kd)
    for (int s = g; s < 27; s += GPC) {
        const int h = s / 3, kd = s - 3 * h;
        float2* base = &buf[(h * 30 + kd) * TC + cl];   // stride over w: 3*TC
        float xr[10], xi[10];
        #pragma unroll
        for (int w = 0; w < 10; ++w) { float2 v = base[w * 3 * TC]; xr[w] = v.x; xi[w] = v.y; }
        float outr[10], outi[10];
        #pragma unroll
        for (int k = 0; k < 10; ++k) {
            float ar = 0.f, ai = 0.f;
            #pragma unroll
            for (int w = 0; w < 10; ++w) {
                const int m = (k * w) % 10;
                ar += xr[w] * C10[m] + xi[w] * S10[m];
                ai += xi[w] * C10[m] - xr[w] * S10[m];
            }
            outr[k] = ar; outi[k] = ai;
        }
        #pragma unroll
        for (int k = 0; k < 10; ++k) base[k * 3 * TC] = make_float2(outr[k], outi[k]);
    }
    __syncthreads();

    // ---------------- S3: fft_H(9) -> xWeight -> ifft_H(9), in registers; 30 sets (kw,kd)
    for (int s = g; s < 30; s += GPC) {
        const int kw = s / 3, kd = s - 3 * kw;
        float2* base = &buf[(kw * 3 + kd) * TC + cl];   // stride over h: 30*TC
        float xr[9], xi[9];
        #pragma unroll
        for (int h = 0; h < 9; ++h) { float2 v = base[h * 30 * TC]; xr[h] = v.x; xi[h] = v.y; }
        float zr[9], zi[9];
        #pragma unroll
        for (int k = 0; k < 9; ++k) {
            float ar = 0.f, ai = 0.f;
            #pragma unroll
            for (int h = 0; h < 9; ++h) {
                const int m = (k * h) % 9;
                ar += xr[h] * C9[m] + xi[h] * S9[m];
                ai += xi[h] * C9[m] - xr[h] * S9[m];
            }
            float wr = 0.f, wi = 0.f;
            if (cv) {
                const float2 wv = *reinterpret_cast<const float2*>(
                    wb + (size_t)((k * 10 + kw) * 3 + kd) * nch * 2);
                wr = wv.x; wi = wv.y;
            }
            zr[k] = ar * wr - ai * wi;
            zi[k] = ar * wi + ai * wr;
        }
        #pragma unroll
        for (int h = 0; h < 9; ++h) {
            float ar = 0.f, ai = 0.f;
            #pragma unroll
            for (int k = 0; k < 9; ++k) {
                const int m = (k * h) % 9;
                ar += zr[k] * C9[m] - zi[k] * S9[m];
                ai += zi[k] * C9[m] + zr[k] * S9[m];
            }
            base[h * 30 * TC] = make_float2(ar, ai);
        }
    }
    __syncthreads();

    // ---------------- S4: inverse 10-pt DFT along W; 27 sets (h,kd)
    for (int s = g; s < 27; s += GPC) {
        const int h = s / 3, kd = s - 3 * h;
        float2* base = &buf[(h * 30 + kd) * TC + cl];
        float xr[10], xi[10];
        #pragma unroll
        for (int w = 0; w < 10; ++w) { float2 v = base[w * 3 * TC]; xr[w] = v.x; xi[w] = v.y; }
        float outr[10], outi[10];
        #pragma unroll
        for (int k = 0; k < 10; ++k) {
            float ar = 0.f, ai = 0.f;
            #pragma unroll
            for (int w = 0; w < 10; ++w) {
                const int m = (k * w) % 10;
                ar += xr[w] * C10[m] - xi[w] * S10[m];
                ai += xi[w] * C10[m] + xr[w] * S10[m];
            }
            outr[k] = ar; outi[k] = ai;
        }
        #pragma unroll
        for (int k = 0; k < 10; ++k) base[k * 3 * TC] = make_float2(outr[k], outi[k]);
    }
    __syncthreads();

    // ---------------- S5: irfft along D (c2r: Im(U0) dropped) + 1/450 + store
    const float sc = 1.0f / 450.0f;
    for (int l = g; l < 90; l += GPC) {
        float2* in = &buf[(l * 3) * TC + cl];
        float2 u0 = in[0], u1 = in[TC], u2 = in[2 * TC];
        if (cv) {
            float* p = yb + (size_t)l * 5 * nch;
            #pragma unroll
            for (int d = 0; d < 5; ++d) {
                const int m1 = d % 5, m2 = (2 * d) % 5;
                float v = u0.x
                        + 2.f * (u1.x * C5[m1] - u1.y * S5[m1])
                        + 2.f * (u2.x * C5[m2] - u2.y * S5[m2]);
                p[(size_t)d * nch] = v * sc;
            }
        }
    }
}

extern "C" void kernel_launch(void* const* d_in, const int* in_sizes, int n_in,
                              void* d_out, int out_size, void* d_ws, size_t ws_size,
                              hipStream_t stream) {
    const float* x  = (const float*)d_in[0];
    const float* cw = (const float*)d_in[1];
    float* y = (float*)d_out;
    const int nch = 1000;
    const int B = in_sizes[0] / (450 * nch);   // 256
    dim3 grid(B, (nch + TC - 1) / TC);         // (256, 32)
    gf_kernel<<<grid, NT, 0, stream>>>(x, cw, y, nch);
}

// Round 3
// 1048.632 us; speedup vs baseline: 1.0458x; 1.0458x over previous
//
#include <hip/hip_runtime.h>

#define TC 16            // channels per block tile (was 32; halves LDS -> 4 blocks/CU)
#define NT 256           // threads per block
#define GPC (NT / TC)    // 16 line-groups per channel tile

// LDS: buf[line(90)][kd(3)][TC] of float2 (re,im) -> 90*3*16*8B = 34560 B
// 34560 B/block -> 4 blocks/CU (160 KiB LDS), 16 waves/CU = 50% occupancy
// (VGPR=128 caps at 4 waves/SIMD, so 50% is the regalloc-consistent target).

__global__ __launch_bounds__(NT, 4)
void gf_kernel(const float* __restrict__ x, const float* __restrict__ cw,
               float* __restrict__ y, int nch)
{
    // twiddle tables: cos/sin(2*pi*m/N); folded to literals after full unroll
    static constexpr float C5[5]  = {1.f, 0.30901699437494745f, -0.8090169943749473f,
                                     -0.8090169943749473f, 0.30901699437494745f};
    static constexpr float S5[5]  = {0.f, 0.9510565162951535f, 0.5877852522924732f,
                                     -0.5877852522924732f, -0.9510565162951535f};
    static constexpr float C10[10] = {1.f, 0.8090169943749474f, 0.30901699437494745f,
                                      -0.30901699437494745f, -0.8090169943749474f, -1.f,
                                      -0.8090169943749474f, -0.30901699437494745f,
                                      0.30901699437494745f, 0.8090169943749474f};
    static constexpr float S10[10] = {0.f, 0.5877852522924731f, 0.9510565162951535f,
                                      0.9510565162951535f, 0.5877852522924731f, 0.f,
                                      -0.5877852522924731f, -0.9510565162951535f,
                                      -0.9510565162951535f, -0.5877852522924731f};
    static constexpr float C9[9] = {1.f, 0.766044443118978f, 0.17364817766693041f, -0.5f,
                                    -0.9396926207859084f, -0.9396926207859084f, -0.5f,
                                    0.17364817766693041f, 0.766044443118978f};
    static constexpr float S9[9] = {0.f, 0.6427876096865393f, 0.984807753012208f,
                                    0.8660254037844387f, 0.3420201433256689f,
                                    -0.3420201433256689f, -0.8660254037844387f,
                                    -0.984807753012208f, -0.6427876096865393f};

    __shared__ float2 buf[90 * 3 * TC];

    const int b  = blockIdx.x;
    const int c0 = blockIdx.y * TC;
    const int t  = threadIdx.x;
    const int cl = t & (TC - 1);
    const int g  = t / TC;                 // 0..GPC-1
    const int c  = c0 + cl;
    const bool cv = (c < nch);

    const float* xb = x + (size_t)b * 450 * nch + c;
    float*       yb = y + (size_t)b * 450 * nch + c;
    const float* wb = cw + (size_t)c * 2;  // weight base for this channel

    // ---------------- S1: rfft along D (5 real -> 3 complex), global -> LDS
    for (int l = g; l < 90; l += GPC) {
        float v0 = 0.f, v1 = 0.f, v2 = 0.f, v3 = 0.f, v4 = 0.f;
        if (cv) {
            const float* p = xb + (size_t)l * 5 * nch;
            v0 = p[0];       v1 = p[nch];     v2 = p[2 * nch];
            v3 = p[3 * nch]; v4 = p[4 * nch];
        }
        float2* out = &buf[(l * 3) * TC + cl];
        out[0] = make_float2(v0 + v1 + v2 + v3 + v4, 0.f);
        // k=1: m = d%5
        float r1 = v0 + v1 * C5[1] + v2 * C5[2] + v3 * C5[3] + v4 * C5[4];
        float i1 = -(v1 * S5[1] + v2 * S5[2] + v3 * S5[3] + v4 * S5[4]);
        out[TC] = make_float2(r1, i1);
        // k=2: m = (2d)%5
        float r2 = v0 + v1 * C5[2] + v2 * C5[4] + v3 * C5[1] + v4 * C5[3];
        float i2 = -(v1 * S5[2] + v2 * S5[4] + v3 * S5[1] + v4 * S5[3]);
        out[2 * TC] = make_float2(r2, i2);
    }
    __syncthreads();

    // ---------------- S2: forward 10-pt DFT along W; 27 sets (h,kd)
    for (int s = g; s < 27; s += GPC) {
        const int h = s / 3, kd = s - 3 * h;
        float2* base = &buf[(h * 30 + kd) * TC + cl];   // stride over w: 3*TC
        float xr[10], xi[10];
        #pragma unroll
        for (int w = 0; w < 10; ++w) { float2 v = base[w * 3 * TC]; xr[w] = v.x; xi[w] = v.y; }
        float outr[10], outi[10];
        #pragma unroll
        for (int k = 0; k < 10; ++k) {
            float ar = 0.f, ai = 0.f;
            #pragma unroll
            for (int w = 0; w < 10; ++w) {
                const int m = (k * w) % 10;
                ar += xr[w] * C10[m] + xi[w] * S10[m];
                ai += xi[w] * C10[m] - xr[w] * S10[m];
            }
            outr[k] = ar; outi[k] = ai;
        }
        #pragma unroll
        for (int k = 0; k < 10; ++k) base[k * 3 * TC] = make_float2(outr[k], outi[k]);
    }
    __syncthreads();

    // ---------------- S3: fft_H(9) -> xWeight -> ifft_H(9), in registers; 30 sets (kw,kd)
    for (int s = g; s < 30; s += GPC) {
        const int kw = s / 3, kd = s - 3 * kw;
        float2* base = &buf[(kw * 3 + kd) * TC + cl];   // stride over h: 30*TC
        float xr[9], xi[9];
        #pragma unroll
        for (int h = 0; h < 9; ++h) { float2 v = base[h * 30 * TC]; xr[h] = v.x; xi[h] = v.y; }
        float zr[9], zi[9];
        #pragma unroll
        for (int k = 0; k < 9; ++k) {
            float ar = 0.f, ai = 0.f;
            #pragma unroll
            for (int h = 0; h < 9; ++h) {
                const int m = (k * h) % 9;
                ar += xr[h] * C9[m] + xi[h] * S9[m];
                ai += xi[h] * C9[m] - xr[h] * S9[m];
            }
            float wr = 0.f, wi = 0.f;
            if (cv) {
                const float2 wv = *reinterpret_cast<const float2*>(
                    wb + (size_t)((k * 10 + kw) * 3 + kd) * nch * 2);
                wr = wv.x; wi = wv.y;
            }
            zr[k] = ar * wr - ai * wi;
            zi[k] = ar * wi + ai * wr;
        }
        #pragma unroll
        for (int h = 0; h < 9; ++h) {
            float ar = 0.f, ai = 0.f;
            #pragma unroll
            for (int k = 0; k < 9; ++k) {
                const int m = (k * h) % 9;
                ar += zr[k] * C9[m] - zi[k] * S9[m];
                ai += zi[k] * C9[m] + zr[k] * S9[m];
            }
            base[h * 30 * TC] = make_float2(ar, ai);
        }
    }
    __syncthreads();

    // ---------------- S4: inverse 10-pt DFT along W; 27 sets (h,kd)
    for (int s = g; s < 27; s += GPC) {
        const int h = s / 3, kd = s - 3 * h;
        float2* base = &buf[(h * 30 + kd) * TC + cl];
        float xr[10], xi[10];
        #pragma unroll
        for (int w = 0; w < 10; ++w) { float2 v = base[w * 3 * TC]; xr[w] = v.x; xi[w] = v.y; }
        float outr[10], outi[10];
        #pragma unroll
        for (int k = 0; k < 10; ++k) {
            float ar = 0.f, ai = 0.f;
            #pragma unroll
            for (int w = 0; w < 10; ++w) {
                const int m = (k * w) % 10;
                ar += xr[w] * C10[m] - xi[w] * S10[m];
                ai += xi[w] * C10[m] + xr[w] * S10[m];
            }
            outr[k] = ar; outi[k] = ai;
        }
        #pragma unroll
        for (int k = 0; k < 10; ++k) base[k * 3 * TC] = make_float2(outr[k], outi[k]);
    }
    __syncthreads();

    // ---------------- S5: irfft along D (c2r: Im(U0) dropped) + 1/450 + store
    const float sc = 1.0f / 450.0f;
    for (int l = g; l < 90; l += GPC) {
        float2* in = &buf[(l * 3) * TC + cl];
        float2 u0 = in[0], u1 = in[TC], u2 = in[2 * TC];
        if (cv) {
            float* p = yb + (size_t)l * 5 * nch;
            #pragma unroll
            for (int d = 0; d < 5; ++d) {
                const int m1 = d % 5, m2 = (2 * d) % 5;
                float v = u0.x
                        + 2.f * (u1.x * C5[m1] - u1.y * S5[m1])
                        + 2.f * (u2.x * C5[m2] - u2.y * S5[m2]);
                p[(size_t)d * nch] = v * sc;
            }
        }
    }
}

extern "C" void kernel_launch(void* const* d_in, const int* in_sizes, int n_in,
                              void* d_out, int out_size, void* d_ws, size_t ws_size,
                              hipStream_t stream) {
    const float* x  = (const float*)d_in[0];
    const float* cw = (const float*)d_in[1];
    float* y = (float*)d_out;
    const int nch = 1000;
    const int B = in_sizes[0] / (450 * nch);   // 256
    dim3 grid(B, (nch + TC - 1) / TC);         // (256, 63)
    gf_kernel<<<grid, NT, 0, stream>>>(x, cw, y, nch);
}